// Round 23
// baseline (449.297 us; speedup 1.0000x reference)
//
#include <hip/hip_runtime.h>

#define DEVI static __device__ __forceinline__

typedef __attribute__((ext_vector_type(4))) float f32x4;
typedef __attribute__((ext_vector_type(2))) float f32x2;
typedef __attribute__((ext_vector_type(8))) __bf16 bf16x8;
typedef __attribute__((ext_vector_type(8))) unsigned short u16x8;
typedef __attribute__((ext_vector_type(4))) unsigned short u16x4;
typedef __attribute__((ext_vector_type(8))) int i32x8;
typedef __attribute__((ext_vector_type(4))) long l64x4;
typedef __attribute__((ext_vector_type(2))) long l64x2;

DEVI unsigned short f2bf(float f) {
  union { float f; unsigned int u; } v; v.f = f;
  unsigned int u = v.u;
  u += 0x7FFFu + ((u >> 16) & 1u);   // RNE
  return (unsigned short)(u >> 16);
}
DEVI float bf2f(unsigned short s) {
  union { unsigned int u; float f; } v; v.u = ((unsigned int)s) << 16;
  return v.f;
}
// Padé(3,2) tanh, clamped at |x|=3 (exact saturation): ONE trans op (rcp)
// instead of exp2->rcp serial pair. |err| <= 3e-3.
DEVI float tanhf_(float x) {
  float xc = fminf(3.0f, fmaxf(-3.0f, x));
  float x2 = xc * xc;
  return xc * (27.0f + x2) * __builtin_amdgcn_rcpf(fmaf(9.0f, x2, 27.0f));
}
DEVI float sigf(float x) {
  float xc = fminf(3.0f, fmaxf(-3.0f, 0.5f * x));
  float x2 = xc * xc;
  float th = xc * (27.0f + x2) * __builtin_amdgcn_rcpf(fmaf(9.0f, x2, 27.0f));
  return fmaf(0.5f, th, 0.5f);
}
DEVI f32x4 mfma_bf16(bf16x8 a, bf16x8 b, f32x4 c) {
  return __builtin_amdgcn_mfma_f32_16x16x32_bf16(a, b, c, 0, 0, 0);
}
// MX-scaled MFMA K=128, scales=1.0 (E8M0 0x7F). 9-arg form:
// (a, b, c, fmtA, fmtB, selA, scaleA, selB, scaleB); fmt: 0=fp8, 4=fp4.
DEVI f32x4 mfma_mx(i32x8 a, i32x8 b, f32x4 c) {
  return __builtin_amdgcn_mfma_scale_f32_16x16x128_f8f6f4(
      a, b, c, 0, 0, 0, 0x7F7F7F7F, 0, 0x7F7F7F7F);
}
DEVI f32x4 mfma_mx4(i32x8 a, i32x8 b, f32x4 c) {   // A fp8, B fp4
  return __builtin_amdgcn_mfma_scale_f32_16x16x128_f8f6f4(
      a, b, c, 0, 4, 0, 0x7F7F7F7F, 0, 0x7F7F7F7F);
}
// fp4 e2m1 encoder (values {0,.5,1,1.5,2,3,4,6}, round-to-nearest)
DEVI unsigned int fp4enc(float x) {
  float f = fabsf(x);
  unsigned int m;
  if      (f <  0.25f) m = 0u;
  else if (f <  0.75f) m = 1u;
  else if (f <  1.25f) m = 2u;
  else if (f <  1.75f) m = 3u;
  else if (f <  2.5f)  m = 4u;
  else if (f <  3.5f)  m = 5u;
  else if (f <  5.0f)  m = 6u;
  else                 m = 7u;
  return m | (x < 0.0f ? 8u : 0u);
}
// LDS-only barrier: does NOT drain vmcnt.
DEVI void lds_barrier() {
  asm volatile("s_waitcnt lgkmcnt(0)" ::: "memory");
  __builtin_amdgcn_s_barrier();
}

// ---------------- K0: prep: wWih->fp8, wWhh->fp4 (permuted), wembed->fp8 ---
// block 0 also zeroes goldacc (stream order: before k_feats adds to it).
__global__ void k_prep(const float* wih_f, const float* wih_b,
                       const float* whh_f, const float* whh_b,
                       const int* sentence, const float* wemb,
                       unsigned short* wcat8, unsigned char* whh4,
                       unsigned char* x8, float* goldacc) {
  int bid = blockIdx.x;
  if (bid == 0 && threadIdx.x == 0) goldacc[0] = 0.0f;
  if (bid < 2560) {                       // wWih cast: 2048x640 -> fp8 pairs
    int i = bid * 256 + threadIdx.x;      // 655,360 pairs
    int e = i * 2;
    int r = e / 640, c = e - r * 640;
    const float* src = (r < 1024) ? wih_f + r * 640 : wih_b + (r - 1024) * 640;
    int p = __builtin_amdgcn_cvt_pk_fp8_f32(src[c] * 16.0f, src[c + 1] * 16.0f, 0, false);
    wcat8[i] = (unsigned short)(p & 0xFFFF);
  } else if (bid < 3584) {                // wWhh -> fp4 x16, A-permutation order
    int i = (bid - 2560) * 256 + threadIdx.x;   // byte index, 262144 total
    int d = i >> 17;
    int r = i & 131071;
    int grow = r >> 7;                    // 128 B per gate-row
    int b = r & 127;
    int kt = b >> 6, rr = b & 63, lhi = rr >> 4, ib = rr & 15;
    int i0 = 2 * ib, i1 = i0 + 1;
    int k0 = kt * 128 + (i0 >> 3) * 32 + lhi * 8 + (i0 & 7);
    int k1 = kt * 128 + (i1 >> 3) * 32 + lhi * 8 + (i1 & 7);
    const float* src = d ? whh_b : whh_f;
    unsigned n0 = fp4enc(src[grow * 256 + k0] * 16.0f);
    unsigned n1 = fp4enc(src[grow * 256 + k1] * 16.0f);
    whh4[i] = (unsigned char)(n0 | (n1 << 4));
  } else {                                // wembed gather -> x8[:,128:640] fp8
    int gid = (bid - 3584) * 256 + threadIdx.x;   // 16384*64
    int row = gid >> 6;
    int c8 = (gid & 63) * 8;
    int b = row & 63, t = row >> 6;
    int sent = sentence[b * 256 + t];
    const float* src = wemb + (long)sent * 512 + c8;
    unsigned long pk = 0;
    #pragma unroll
    for (int e = 0; e < 8; e += 2) {
      int p2 = __builtin_amdgcn_cvt_pk_fp8_f32(src[e] * 16.0f, src[e + 1] * 16.0f, 0, false);
      pk |= ((unsigned long)(p2 & 0xFFFF)) << (e * 8);
    }
    *(unsigned long*)&x8[row * 640 + 128 + c8] = pk;
  }
}

// ---------------- K1: fused char embed + char BiLSTM -> x8[:,0:128] --------
DEVI bf16x8 load_wfrag(const float* Wm, int rowbase, int l15, int lhi, int ks) {
  const float* p = Wm + (rowbase + l15) * 64 + ks * 32 + lhi * 8;
  u16x8 u;
  #pragma unroll
  for (int e = 0; e < 8; ++e) u[e] = f2bf(p[e]);
  return __builtin_bit_cast(bf16x8, u);
}

__launch_bounds__(256, 1)
__global__ void k_char_lstm(const int* chars, const float* cemb,
                            const float* cWih_f, const float* cWhh_f, const float* cb_f,
                            const float* cWih_b, const float* cWhh_b, const float* cb_b,
                            const float* h0c, const float* c0c,
                            unsigned char* x8) {
  __shared__ unsigned short embT[128 * 64];
  __shared__ int charsT[16 * 64];
  __shared__ unsigned short hT[64 * 72];
  const int tid = threadIdx.x;
  const int w = tid >> 6, lane = tid & 63;
  const int l15 = lane & 15, lhi = lane >> 4;
  const int sbase = blockIdx.x * 64;

  for (int idx = tid; idx < 8192; idx += 256) embT[idx] = f2bf(cemb[idx]);
  for (int idx = tid; idx < 1024; idx += 256) {
    int s = idx >> 4, t = idx & 15;
    charsT[t * 64 + s] = chars[(sbase + s) * 16 + t];
  }
  for (int idx = tid; idx < 4096; idx += 256) {
    int s = idx >> 6, u = idx & 63;
    hT[s * 72 + u] = f2bf(h0c[(sbase + s) * 64 + u]);
  }
  bf16x8 bih[4][2], bhh[4][2];
  float bias[4];
  #pragma unroll
  for (int q = 0; q < 4; ++q) {
    bias[q] = cb_f[q * 64 + w * 16 + l15];
    #pragma unroll
    for (int ks = 0; ks < 2; ++ks) {
      bih[q][ks] = load_wfrag(cWih_f, (w + 4 * q) * 16, l15, lhi, ks);
      bhh[q][ks] = load_wfrag(cWhh_f, (w + 4 * q) * 16, l15, lhi, ks);
    }
  }
  float c_[4][4];
  #pragma unroll
  for (int mt = 0; mt < 4; ++mt)
    #pragma unroll
    for (int i = 0; i < 4; ++i)
      c_[mt][i] = c0c[(sbase + mt * 16 + lhi * 4 + i) * 64 + w * 16 + l15];
  float hfin[4][4];
  #pragma unroll
  for (int mt = 0; mt < 4; ++mt)
    #pragma unroll
    for (int i = 0; i < 4; ++i) hfin[mt][i] = 0.0f;
  __syncthreads();

  for (int t = 0; t < 16; ++t) {
    bf16x8 ax[4][2], ah[4][2];
    #pragma unroll
    for (int mt = 0; mt < 4; ++mt) {
      int cidx = charsT[t * 64 + mt * 16 + l15];
      #pragma unroll
      for (int ks = 0; ks < 2; ++ks) {
        ax[mt][ks] = __builtin_bit_cast(bf16x8, *(const u16x8*)&embT[cidx * 64 + ks * 32 + lhi * 8]);
        ah[mt][ks] = __builtin_bit_cast(bf16x8, *(const u16x8*)&hT[(mt * 16 + l15) * 72 + ks * 32 + lhi * 8]);
      }
    }
    f32x4 acc[4][4];
    #pragma unroll
    for (int mt = 0; mt < 4; ++mt)
      #pragma unroll
      for (int q = 0; q < 4; ++q) acc[mt][q] = (f32x4){0.f, 0.f, 0.f, 0.f};
    #pragma unroll
    for (int ks = 0; ks < 2; ++ks)
      #pragma unroll
      for (int mt = 0; mt < 4; ++mt)
        #pragma unroll
        for (int q = 0; q < 4; ++q) {
          acc[mt][q] = mfma_bf16(ax[mt][ks], bih[q][ks], acc[mt][q]);
          acc[mt][q] = mfma_bf16(ah[mt][ks], bhh[q][ks], acc[mt][q]);
        }
    __syncthreads();
    #pragma unroll
    for (int mt = 0; mt < 4; ++mt)
      #pragma unroll
      for (int i = 0; i < 4; ++i) {
        float gi = acc[mt][0][i] + bias[0];
        float gf = acc[mt][1][i] + bias[1];
        float gg = acc[mt][2][i] + bias[2];
        float go = acc[mt][3][i] + bias[3];
        float cn = sigf(gf) * c_[mt][i] + sigf(gi) * tanhf_(gg);
        float h = sigf(go) * tanhf_(cn);
        c_[mt][i] = cn;
        if (t == 15) hfin[mt][i] = h;
        hT[(mt * 16 + lhi * 4 + i) * 72 + w * 16 + l15] = f2bf(h);
      }
    __syncthreads();
  }
  #pragma unroll
  for (int mt = 0; mt < 4; ++mt)
    #pragma unroll
    for (int i = 0; i < 4; ++i) {
      int sg = sbase + mt * 16 + lhi * 4 + i;
      int xrow = (sg & 255) * 64 + (sg >> 8);
      int p = __builtin_amdgcn_cvt_pk_fp8_f32(hfin[mt][i] * 16.0f, 0.0f, 0, false);
      x8[xrow * 640 + w * 16 + l15] = (unsigned char)(p & 0xFF);
    }
  #pragma unroll
  for (int q = 0; q < 4; ++q) {
    bias[q] = cb_b[q * 64 + w * 16 + l15];
    #pragma unroll
    for (int ks = 0; ks < 2; ++ks) {
      bih[q][ks] = load_wfrag(cWih_b, (w + 4 * q) * 16, l15, lhi, ks);
      bhh[q][ks] = load_wfrag(cWhh_b, (w + 4 * q) * 16, l15, lhi, ks);
    }
  }
  __syncthreads();
  for (int idx = tid; idx < 4096; idx += 256) {
    int s = idx >> 6, u = idx & 63;
    hT[s * 72 + u] = f2bf(h0c[16384 * 64 + (sbase + s) * 64 + u]);
  }
  __syncthreads();
  {
    bf16x8 ax[4][2], ah[4][2];
    #pragma unroll
    for (int mt = 0; mt < 4; ++mt) {
      int cidx = charsT[15 * 64 + mt * 16 + l15];
      #pragma unroll
      for (int ks = 0; ks < 2; ++ks) {
        ax[mt][ks] = __builtin_bit_cast(bf16x8, *(const u16x8*)&embT[cidx * 64 + ks * 32 + lhi * 8]);
        ah[mt][ks] = __builtin_bit_cast(bf16x8, *(const u16x8*)&hT[(mt * 16 + l15) * 72 + ks * 32 + lhi * 8]);
      }
    }
    f32x4 acc[4][4];
    #pragma unroll
    for (int mt = 0; mt < 4; ++mt)
      #pragma unroll
      for (int q = 0; q < 4; ++q) acc[mt][q] = (f32x4){0.f, 0.f, 0.f, 0.f};
    #pragma unroll
    for (int ks = 0; ks < 2; ++ks)
      #pragma unroll
      for (int mt = 0; mt < 4; ++mt)
        #pragma unroll
        for (int q = 0; q < 4; ++q) {
          acc[mt][q] = mfma_bf16(ax[mt][ks], bih[q][ks], acc[mt][q]);
          acc[mt][q] = mfma_bf16(ah[mt][ks], bhh[q][ks], acc[mt][q]);
        }
    #pragma unroll
    for (int mt = 0; mt < 4; ++mt)
      #pragma unroll
      for (int i = 0; i < 4; ++i) {
        float cc = c0c[16384 * 64 + (sbase + mt * 16 + lhi * 4 + i) * 64 + w * 16 + l15];
        float gi = acc[mt][0][i] + bias[0];
        float gf = acc[mt][1][i] + bias[1];
        float gg = acc[mt][2][i] + bias[2];
        float go = acc[mt][3][i] + bias[3];
        float cn = sigf(gf) * cc + sigf(gi) * tanhf_(gg);
        float h = sigf(go) * tanhf_(cn);
        int sg = sbase + mt * 16 + lhi * 4 + i;
        int xrow = (sg & 255) * 64 + (sg >> 8);
        int p = __builtin_amdgcn_cvt_pk_fp8_f32(h * 16.0f, 0.0f, 0, false);
        x8[xrow * 640 + 64 + w * 16 + l15] = (unsigned char)(p & 0xFF);
      }
  }
}

// ---------------- K3: pre-gates GEMM, MX-fp8 K=128 (unchanged) -------------
__launch_bounds__(256, 2)
__global__ void k_gemm_pre(const unsigned char* x8, const unsigned char* w8,
                           const float* wb_f, const float* wb_b,
                           unsigned short* pre2) {
  __shared__ __align__(16) unsigned char ldsA[2][128 * 144];
  __shared__ __align__(16) unsigned char ldsB[2][128 * 144];
  const int tid = threadIdx.x;
  const int bm = blockIdx.x >> 4, bn = blockIdx.x & 15;
  const int m0 = bm * 128, n0 = bn * 128;
  const int lane = tid & 63, w = tid >> 6;
  const int l15 = lane & 15, lhi = lane >> 4;
  const int wm = (w & 1) * 64, wn = (w >> 1) * 64;

  u16x8 ra[4], rb[4];
  auto gload = [&](int kt) {
    #pragma unroll
    for (int i = 0; i < 4; ++i) {
      int c = i * 256 + tid;
      int row = c >> 3, cb = (c & 7) * 16;
      ra[i] = *(const u16x8*)&x8[(m0 + row) * 640 + kt * 128 + cb];
      rb[i] = *(const u16x8*)&w8[(n0 + row) * 640 + kt * 128 + cb];
    }
  };
  auto swrite = [&](int buf) {
    #pragma unroll
    for (int i = 0; i < 4; ++i) {
      int c = i * 256 + tid;
      int row = c >> 3, cb = (c & 7) * 16;
      *(u16x8*)&ldsA[buf][row * 144 + cb] = ra[i];
      *(u16x8*)&ldsB[buf][row * 144 + cb] = rb[i];
    }
  };
  f32x4 acc[4][4];
  #pragma unroll
  for (int a = 0; a < 4; ++a)
    #pragma unroll
    for (int bb = 0; bb < 4; ++bb) acc[a][bb] = (f32x4){0.f, 0.f, 0.f, 0.f};

  gload(0); swrite(0); __syncthreads();
  for (int kt = 0; kt < 5; ++kt) {
    int cur = kt & 1;
    if (kt < 4) gload(kt + 1);
    i32x8 af[4], bfv[4];
    #pragma unroll
    for (int mt = 0; mt < 4; ++mt)
      af[mt] = __builtin_bit_cast(i32x8,
          *(const l64x4*)&ldsA[cur][(wm + mt * 16 + l15) * 144 + lhi * 32]);
    #pragma unroll
    for (int nt = 0; nt < 4; ++nt)
      bfv[nt] = __builtin_bit_cast(i32x8,
          *(const l64x4*)&ldsB[cur][(wn + nt * 16 + l15) * 144 + lhi * 32]);
    #pragma unroll
    for (int mt = 0; mt < 4; ++mt)
      #pragma unroll
      for (int nt = 0; nt < 4; ++nt)
        acc[mt][nt] = mfma_mx(af[mt], bfv[nt], acc[mt][nt]);
    __syncthreads();
    if (kt < 4) { swrite(cur ^ 1); __syncthreads(); }
  }
  const float inv = 1.0f / 256.0f;
  #pragma unroll
  for (int nt = 0; nt < 4; ++nt) {
    int col = n0 + wn + nt * 16 + l15;
    float bias = (col < 1024) ? wb_f[col] : wb_b[col - 1024];
    #pragma unroll
    for (int mt = 0; mt < 4; ++mt) {
      int row = m0 + wm + mt * 16 + lhi * 4;
      int t = row >> 6, b = row & 63, rg = b >> 3, b8 = b & 7;
      u16x4 v;
      #pragma unroll
      for (int i = 0; i < 4; ++i) v[i] = f2bf(acc[mt][nt][i] * inv + bias);
      *(u16x4*)&pre2[((long)(rg * 256 + t) * 2048 + col) * 8 + b8] = v;
    }
  }
}

// ---------------- K4: word LSTM recurrence v11 (fp8 A x fp4 B, Padé gates) -
#define LSTM_STEP(SRC, DST, PU, TT)                                          \
  {                                                                          \
    long a8[8];                                                              \
    _Pragma("unroll")                                                        \
    for (int ks = 0; ks < 8; ++ks)                                           \
      a8[ks] = *(const long*)&SRC[l15 * 264 + ks * 32 + lhi * 8];            \
    l64x4 alo4 = {a8[0], a8[1], a8[2], a8[3]};                               \
    l64x4 ahi4 = {a8[4], a8[5], a8[6], a8[7]};                               \
    i32x8 aLo = __builtin_bit_cast(i32x8, alo4);                             \
    i32x8 aHi = __builtin_bit_cast(i32x8, ahi4);                             \
    f32x4 accA[4], accB[4];                                                  \
    _Pragma("unroll")                                                        \
    for (int g = 0; g < 4; ++g) {                                            \
      accA[g] = mfma_mx4(aLo, bfr4[g][0], (f32x4){0.f, 0.f, 0.f, 0.f});      \
      accB[g] = mfma_mx4(aHi, bfr4[g][1], (f32x4){0.f, 0.f, 0.f, 0.f});      \
    }                                                                        \
    float gi = fmaf(accA[0][0] + accB[0][0], inv, bf2f(PU[0]));              \
    float gf = fmaf(accA[1][0] + accB[1][0], inv, bf2f(PU[1]));              \
    float gg = fmaf(accA[2][0] + accB[2][0], inv, bf2f(PU[2]));              \
    float go = fmaf(accA[3][0] + accB[3][0], inv, bf2f(PU[3]));              \
    float cn = sigf(gf) * c1 + sigf(gi) * tanhf_(gg);                        \
    float h = sigf(go) * tanhf_(cn);                                         \
    c1 = cn;                                                                 \
    int p2 = __builtin_amdgcn_cvt_pk_fp8_f32(h * 16.0f, 0.0f, 0, false);     \
    DST[(4 * lhi) * 264 + uu] = (unsigned char)(p2 & 0xFF);                  \
    hout[((long)(TT) * 64 + row0 + lhi) * 512 + dco] = f2bf(h);              \
  }

__launch_bounds__(1024, 4)
__global__ void k_word_lstm(const unsigned char* whh4, const unsigned short* pre2,
                            const float* h0w, const float* c0w,
                            unsigned short* hout, float* cstate, int t0) {
  __shared__ __align__(16) unsigned char hlds[2][16 * 264];   // fp8 h, x16 scale
  const int tid = threadIdx.x;
  const int w = tid >> 6, lane = tid & 63;
  const int l15 = lane & 15, lhi = lane >> 4;
  const int dir = blockIdx.x >> 4, rg = blockIdx.x & 15;
  const int row0 = rg * 4;
  const int uu = w * 16 + l15;
  const int dco = dir * 256 + uu;
  const bool first = (t0 == 0);
  const unsigned char* W4 = whh4 + dir * 131072;

  i32x8 bfr4[4][2];   // resident fp4 weights (16B each, low 4 dwords)
  #pragma unroll
  for (int g = 0; g < 4; ++g) {
    int grow = g * 256 + uu;
    #pragma unroll
    for (int kt = 0; kt < 2; ++kt) {
      l64x2 v2 = *(const l64x2*)(W4 + grow * 128 + kt * 64 + lhi * 16);
      l64x4 v = {v2[0], v2[1], 0, 0};
      bfr4[g][kt] = __builtin_bit_cast(i32x8, v);
    }
  }
  for (int idx = tid; idx < 2112; idx += 1024)
    ((unsigned int*)&hlds[0][0])[idx] = 0;
  __syncthreads();
  {
    int r = tid >> 8, u0 = tid & 255;
    float hv;
    if (first) {
      hv = h0w[dir * 16384 + (row0 + r) * 256 + u0];
    } else {
      int tb = dir ? (256 - t0) : (t0 - 1);
      hv = bf2f(hout[((long)tb * 64 + row0 + r) * 512 + dir * 256 + u0]);
    }
    int p = __builtin_amdgcn_cvt_pk_fp8_f32(hv * 16.0f, 0.0f, 0, false);
    hlds[0][(4 * r) * 264 + u0] = (unsigned char)(p & 0xFF);
  }
  float c1 = first ? c0w[dir * 16384 + (row0 + lhi) * 256 + uu]
                   : cstate[blockIdx.x * 1024 + tid];

  const unsigned short* pgBase =
      pre2 + (long)(rg >> 1) * 256 * 2048 * 8 + (dir * 1024 + uu) * 8 + (rg & 1) * 4 + lhi;

  unsigned short pA[4], pB[4];
  const int ttA0 = dir ? (255 - t0) : t0;
  #pragma unroll
  for (int g = 0; g < 4; ++g)
    pA[g] = pgBase[(long)ttA0 * 16384 + g * 2048];
  __syncthreads();

  const float inv = 1.0f / 256.0f;
  for (int tl = 0; tl < 128; tl += 2) {
    const int tg = t0 + tl;
    const int ttA = dir ? (255 - tg) : tg;
    const int ttB = dir ? (254 - tg) : (tg + 1);
    int ttC = dir ? (253 - tg) : (tg + 2);
    ttC = ttC < 0 ? 0 : (ttC > 255 ? 255 : ttC);
    #pragma unroll
    for (int g = 0; g < 4; ++g)
      pB[g] = pgBase[(long)ttB * 16384 + g * 2048];
    LSTM_STEP(hlds[0], hlds[1], pA, ttA)
    lds_barrier();
    #pragma unroll
    for (int g = 0; g < 4; ++g)
      pA[g] = pgBase[(long)ttC * 16384 + g * 2048];
    LSTM_STEP(hlds[1], hlds[0], pB, ttB)
    lds_barrier();
  }
  cstate[blockIdx.x * 1024 + tid] = c1;
}

// ---------------- K5: feats + gold fold ------------------------------------
__launch_bounds__(256, 2)
__global__ void k_feats(const unsigned short* hbuf, const float* Wtag, const float* btag,
                        const int* tags, const float* trans,
                        float* feats, float* goldacc) {
  __shared__ float red[256];
  const int tid = threadIdx.x;
  const int w = tid >> 6, lane = tid & 63, l15 = lane & 15, lhi = lane >> 4;
  const int m0 = blockIdx.x * 64 + w * 16;
  const int t = blockIdx.x;
  bf16x8 bfr[16];
  #pragma unroll
  for (int ks = 0; ks < 16; ++ks) {
    u16x8 u;
    if (l15 < 12) {
      const float* p = Wtag + l15 * 512 + ks * 32 + lhi * 8;
      #pragma unroll
      for (int e = 0; e < 8; ++e) u[e] = f2bf(p[e]);
    } else {
      #pragma unroll
      for (int e = 0; e < 8; ++e) u[e] = 0;
    }
    bfr[ks] = __builtin_bit_cast(bf16x8, u);
  }
  f32x4 acc = {0.f, 0.f, 0.f, 0.f};
  #pragma unroll
  for (int ks = 0; ks < 16; ++ks) {
    u16x8 a = *(const u16x8*)&hbuf[(m0 + l15) * 512 + ks * 32 + lhi * 8];
    acc = mfma_bf16(__builtin_bit_cast(bf16x8, a), bfr[ks], acc);
  }
  float bias = (l15 < 12) ? btag[l15] : 0.0f;
  float g = 0.0f;
  #pragma unroll
  for (int i = 0; i < 4; ++i) {
    float fv = acc[i] + bias;
    feats[(m0 + lhi * 4 + i) * 16 + l15] = fv;
    int b = w * 16 + lhi * 4 + i;          // batch index (block = one t)
    int tg = tags[b * 256 + t];
    if (l15 == tg) g += fv;
    if (l15 == 0) {
      int pv = (t == 0) ? 0 : tags[b * 256 + t - 1];
      g += trans[tg * 12 + pv];
      if (t == 255) g += trans[2 * 12 + tg];
    }
  }
  red[tid] = g;
  __syncthreads();
  for (int st = 128; st > 0; st >>= 1) {
    if (tid < st) red[tid] += red[tid + st];
    __syncthreads();
  }
  if (tid == 0) atomicAdd(goldacc, red[0]);
}

// ---------------- K6: CRF v5 — packed-f32 exp-domain, gold pre-folded ------
#define LOADE2(R)                                                            \
  _Pragma("unroll")                                                          \
  for (int k = 0; k < 6; ++k) {                                              \
    E##R[k][0] = __builtin_amdgcn_exp2f(LOG2E * trans[R * 12 + 2 * k]);      \
    E##R[k][1] = __builtin_amdgcn_exp2f(LOG2E * trans[R * 12 + 2 * k + 1]);  \
  }
#define DOTE2(R)                                                             \
  {                                                                          \
    f32x2 d2 = E##R[0] * pv[0];                                              \
    _Pragma("unroll")                                                        \
    for (int k = 1; k < 6; ++k)                                              \
      d2 = __builtin_elementwise_fma(E##R[k], pv[k], d2);                    \
    np[R] = em[R] * (d2[0] + d2[1]);                                         \
  }

__launch_bounds__(64, 1)
__global__ void k_crf(const float* feats, const float* trans, const float* goldacc,
                      float* out) {
  const int lane = threadIdx.x;   // batch 0..63
  const float LOG2E = 1.44269504089f, LN2 = 0.69314718056f;
  f32x2 E0[6], E1[6], E2[6], E3[6], E4[6], E5[6],
        E6[6], E7[6], E8[6], E9[6], E10[6], E11[6];
  float tr2[12];
  LOADE2(0) LOADE2(1) LOADE2(2) LOADE2(3) LOADE2(4) LOADE2(5)
  LOADE2(6) LOADE2(7) LOADE2(8) LOADE2(9) LOADE2(10) LOADE2(11)
  #pragma unroll
  for (int j = 0; j < 12; ++j) tr2[j] = trans[2 * 12 + j];

  f32x2 pv[6];
  pv[0] = (f32x2){1.0f, 0.0f};
  #pragma unroll
  for (int k = 1; k < 6; ++k) pv[k] = (f32x2){0.0f, 0.0f};
  float logZ = 0.0f;
  const float* fp = feats + lane * 16;
  f32x4 c0 = *(const f32x4*)(fp);
  f32x4 c1 = *(const f32x4*)(fp + 4);
  f32x4 c2 = *(const f32x4*)(fp + 8);
  for (int t = 0; t < 256; ++t) {
    const float* npf = fp + (long)(t + 1) * 1024;   // t=255 strays into wcat8, ok
    f32x4 n0 = *(const f32x4*)(npf);
    f32x4 n1 = *(const f32x4*)(npf + 4);
    f32x4 n2 = *(const f32x4*)(npf + 8);
    float em[12];
    em[0] = __builtin_amdgcn_exp2f(LOG2E * c0[0]);
    em[1] = __builtin_amdgcn_exp2f(LOG2E * c0[1]);
    em[2] = __builtin_amdgcn_exp2f(LOG2E * c0[2]);
    em[3] = __builtin_amdgcn_exp2f(LOG2E * c0[3]);
    em[4] = __builtin_amdgcn_exp2f(LOG2E * c1[0]);
    em[5] = __builtin_amdgcn_exp2f(LOG2E * c1[1]);
    em[6] = __builtin_amdgcn_exp2f(LOG2E * c1[2]);
    em[7] = __builtin_amdgcn_exp2f(LOG2E * c1[3]);
    em[8] = __builtin_amdgcn_exp2f(LOG2E * c2[0]);
    em[9] = __builtin_amdgcn_exp2f(LOG2E * c2[1]);
    em[10] = __builtin_amdgcn_exp2f(LOG2E * c2[2]);
    em[11] = __builtin_amdgcn_exp2f(LOG2E * c2[3]);
    float np[12];
    DOTE2(0) DOTE2(1) DOTE2(2) DOTE2(3) DOTE2(4) DOTE2(5)
    DOTE2(6) DOTE2(7) DOTE2(8) DOTE2(9) DOTE2(10) DOTE2(11)
    if ((t & 3) == 3) {       // renormalize
      float s = fmaxf(fmaxf(
          fmaxf(fmaxf(np[0], np[1]), fmaxf(np[2], np[3])),
          fmaxf(fmaxf(np[4], np[5]), fmaxf(np[6], np[7]))),
          fmaxf(fmaxf(np[8], np[9]), fmaxf(np[10], np[11])));
      float r = __builtin_amdgcn_rcpf(s);
      #pragma unroll
      for (int j = 0; j < 12; ++j) np[j] *= r;
      logZ += __builtin_amdgcn_logf(s);
    }
    #pragma unroll
    for (int k = 0; k < 6; ++k) pv[k] = (f32x2){np[2 * k], np[2 * k + 1]};
    c0 = n0; c1 = n1; c2 = n2;
  }
  float s = 0.0f;
  #pragma unroll
  for (int k = 0; k < 6; ++k) {
    s = fmaf(pv[k][0], __builtin_amdgcn_exp2f(LOG2E * tr2[2 * k]), s);
    s = fmaf(pv[k][1], __builtin_amdgcn_exp2f(LOG2E * tr2[2 * k + 1]), s);
  }
  float part = LN2 * (logZ + __builtin_amdgcn_logf(s));
  #pragma unroll
  for (int d = 1; d < 64; d <<= 1) part += __shfl_xor(part, d, 64);
  if (lane == 0) out[0] = (part - goldacc[0]) / 64.0f;
}

// ---------------------------------------------------------------------------
extern "C" void kernel_launch(void* const* d_in, const int* in_sizes, int n_in,
                              void* d_out, int out_size, void* d_ws, size_t ws_size,
                              hipStream_t stream) {
  const int*   sentence = (const int*)d_in[0];
  const int*   chars    = (const int*)d_in[1];
  const int*   tags     = (const int*)d_in[2];
  const float* wemb     = (const float*)d_in[3];
  const float* cemb     = (const float*)d_in[4];
  const float* cWih_f   = (const float*)d_in[5];
  const float* cWhh_f   = (const float*)d_in[6];
  const float* cb_f     = (const float*)d_in[7];
  const float* cWih_b   = (const float*)d_in[8];
  const float* cWhh_b   = (const float*)d_in[9];
  const float* cb_b     = (const float*)d_in[10];
  const float* wWih_f   = (const float*)d_in[11];
  const float* wWhh_f   = (const float*)d_in[12];
  const float* wb_f     = (const float*)d_in[13];
  const float* wWih_b   = (const float*)d_in[14];
  const float* wWhh_b   = (const float*)d_in[15];
  const float* wb_b     = (const float*)d_in[16];
  const float* Wtag     = (const float*)d_in[17];
  const float* btag     = (const float*)d_in[18];
  const float* trans    = (const float*)d_in[19];
  const float* h0c      = (const float*)d_in[20];
  const float* c0c      = (const float*)d_in[21];
  const float* h0w      = (const float*)d_in[22];
  const float* c0w      = (const float*)d_in[23];

  char* ws = (char*)d_ws;
  unsigned char*  x8    = (unsigned char*)(ws);                  // 10,485,760 B
  unsigned short* pre2  = (unsigned short*)(ws + 20971520);      // 67,108,864 B
  unsigned short* hbuf  = (unsigned short*)(ws + 88080384);      // 16,777,216 B
  float*          feats = (float*)(ws + 104857600);              //  1,048,576 B
  unsigned short* wcat8 = (unsigned short*)(ws + 105906176);     //  1,310,720 B (fp8)
  unsigned char*  whh4  = (unsigned char*)(ws + 108527616);      //    262,144 B (fp4)
  float*          cstate= (float*)(ws + 108789760);              //    131,072 B
  float*          goldacc = (float*)(ws + 108920832);            //          4 B

  hipLaunchKernelGGL(k_prep, dim3(7680), dim3(256), 0, stream,
                     wWih_f, wWih_b, wWhh_f, wWhh_b, sentence, wemb, wcat8, whh4, x8,
                     goldacc);
  hipLaunchKernelGGL(k_char_lstm, dim3(256), dim3(256), 0, stream, chars, cemb,
                     cWih_f, cWhh_f, cb_f, cWih_b, cWhh_b, cb_b, h0c, c0c, x8);
  hipLaunchKernelGGL(k_gemm_pre, dim3(2048), dim3(256), 0, stream,
                     x8, (const unsigned char*)wcat8, wb_f, wb_b, pre2);
  hipLaunchKernelGGL(k_word_lstm, dim3(32), dim3(1024), 0, stream,
                     whh4, pre2, h0w, c0w, hbuf, cstate, 0);
  hipLaunchKernelGGL(k_word_lstm, dim3(32), dim3(1024), 0, stream,
                     whh4, pre2, h0w, c0w, hbuf, cstate, 128);
  hipLaunchKernelGGL(k_feats, dim3(256), dim3(256), 0, stream, hbuf, Wtag, btag,
                     tags, trans, feats, goldacc);
  hipLaunchKernelGGL(k_crf, dim3(1), dim3(64), 0, stream, feats, trans, goldacc,
                     (float*)d_out);
}

// Round 24
// 442.210 us; speedup vs baseline: 1.0160x; 1.0160x over previous
//
#include <hip/hip_runtime.h>

#define DEVI static __device__ __forceinline__

typedef __attribute__((ext_vector_type(4))) float f32x4;
typedef __attribute__((ext_vector_type(2))) float f32x2;
typedef __attribute__((ext_vector_type(8))) __bf16 bf16x8;
typedef __attribute__((ext_vector_type(8))) unsigned short u16x8;
typedef __attribute__((ext_vector_type(4))) unsigned short u16x4;
typedef __attribute__((ext_vector_type(8))) int i32x8;
typedef __attribute__((ext_vector_type(4))) long l64x4;
typedef __attribute__((ext_vector_type(2))) long l64x2;

DEVI unsigned short f2bf(float f) {
  union { float f; unsigned int u; } v; v.f = f;
  unsigned int u = v.u;
  u += 0x7FFFu + ((u >> 16) & 1u);   // RNE
  return (unsigned short)(u >> 16);
}
DEVI float bf2f(unsigned short s) {
  union { unsigned int u; float f; } v; v.u = ((unsigned int)s) << 16;
  return v.f;
}
// branch-free fast sigmoid/tanh (R20-verified best)
DEVI float sigf(float x) {
  return __builtin_amdgcn_rcpf(1.0f + __builtin_amdgcn_exp2f(-1.44269504089f * x));
}
DEVI float tanhf_(float x) {
  return 1.0f - 2.0f * __builtin_amdgcn_rcpf(1.0f + __builtin_amdgcn_exp2f(2.88539008178f * x));
}
DEVI f32x4 mfma_bf16(bf16x8 a, bf16x8 b, f32x4 c) {
  return __builtin_amdgcn_mfma_f32_16x16x32_bf16(a, b, c, 0, 0, 0);
}
// MX-scaled MFMA K=128, scales=1.0 (E8M0 0x7F). 9-arg form:
// (a, b, c, fmtA, fmtB, selA, scaleA, selB, scaleB); fmt: 0=fp8, 4=fp4.
DEVI f32x4 mfma_mx(i32x8 a, i32x8 b, f32x4 c) {
  return __builtin_amdgcn_mfma_scale_f32_16x16x128_f8f6f4(
      a, b, c, 0, 0, 0, 0x7F7F7F7F, 0, 0x7F7F7F7F);
}
DEVI f32x4 mfma_mx4(i32x8 a, i32x8 b, f32x4 c) {   // A fp8, B fp4
  return __builtin_amdgcn_mfma_scale_f32_16x16x128_f8f6f4(
      a, b, c, 0, 4, 0, 0x7F7F7F7F, 0, 0x7F7F7F7F);
}
// fp4 e2m1 encoder (values {0,.5,1,1.5,2,3,4,6}, round-to-nearest)
DEVI unsigned int fp4enc(float x) {
  float f = fabsf(x);
  unsigned int m;
  if      (f <  0.25f) m = 0u;
  else if (f <  0.75f) m = 1u;
  else if (f <  1.25f) m = 2u;
  else if (f <  1.75f) m = 3u;
  else if (f <  2.5f)  m = 4u;
  else if (f <  3.5f)  m = 5u;
  else if (f <  5.0f)  m = 6u;
  else                 m = 7u;
  return m | (x < 0.0f ? 8u : 0u);
}
// LDS-only barrier: does NOT drain vmcnt.
DEVI void lds_barrier() {
  asm volatile("s_waitcnt lgkmcnt(0)" ::: "memory");
  __builtin_amdgcn_s_barrier();
}

// ---------------- K0: prep: wWih->fp8, wWhh->fp4 (permuted), wembed->fp8 ---
// block 0 also zeroes goldacc (stream order: before k_feats adds to it).
__global__ void k_prep(const float* wih_f, const float* wih_b,
                       const float* whh_f, const float* whh_b,
                       const int* sentence, const float* wemb,
                       unsigned short* wcat8, unsigned char* whh4,
                       unsigned char* x8, float* goldacc) {
  int bid = blockIdx.x;
  if (bid == 0 && threadIdx.x == 0) goldacc[0] = 0.0f;
  if (bid < 2560) {                       // wWih cast: 2048x640 -> fp8 pairs
    int i = bid * 256 + threadIdx.x;      // 655,360 pairs
    int e = i * 2;
    int r = e / 640, c = e - r * 640;
    const float* src = (r < 1024) ? wih_f + r * 640 : wih_b + (r - 1024) * 640;
    int p = __builtin_amdgcn_cvt_pk_fp8_f32(src[c] * 16.0f, src[c + 1] * 16.0f, 0, false);
    wcat8[i] = (unsigned short)(p & 0xFFFF);
  } else if (bid < 3584) {                // wWhh -> fp4 x16, A-permutation order
    int i = (bid - 2560) * 256 + threadIdx.x;   // byte index, 262144 total
    int d = i >> 17;
    int r = i & 131071;
    int grow = r >> 7;                    // 128 B per gate-row
    int b = r & 127;
    int kt = b >> 6, rr = b & 63, lhi = rr >> 4, ib = rr & 15;
    int i0 = 2 * ib, i1 = i0 + 1;
    int k0 = kt * 128 + (i0 >> 3) * 32 + lhi * 8 + (i0 & 7);
    int k1 = kt * 128 + (i1 >> 3) * 32 + lhi * 8 + (i1 & 7);
    const float* src = d ? whh_b : whh_f;
    unsigned n0 = fp4enc(src[grow * 256 + k0] * 16.0f);
    unsigned n1 = fp4enc(src[grow * 256 + k1] * 16.0f);
    whh4[i] = (unsigned char)(n0 | (n1 << 4));
  } else {                                // wembed gather -> x8[:,128:640] fp8
    int gid = (bid - 3584) * 256 + threadIdx.x;   // 16384*64
    int row = gid >> 6;
    int c8 = (gid & 63) * 8;
    int b = row & 63, t = row >> 6;
    int sent = sentence[b * 256 + t];
    const float* src = wemb + (long)sent * 512 + c8;
    unsigned long pk = 0;
    #pragma unroll
    for (int e = 0; e < 8; e += 2) {
      int p2 = __builtin_amdgcn_cvt_pk_fp8_f32(src[e] * 16.0f, src[e + 1] * 16.0f, 0, false);
      pk |= ((unsigned long)(p2 & 0xFFFF)) << (e * 8);
    }
    *(unsigned long*)&x8[row * 640 + 128 + c8] = pk;
  }
}

// ---------------- K1: fused char embed + char BiLSTM -> x8[:,0:128] --------
DEVI bf16x8 load_wfrag(const float* Wm, int rowbase, int l15, int lhi, int ks) {
  const float* p = Wm + (rowbase + l15) * 64 + ks * 32 + lhi * 8;
  u16x8 u;
  #pragma unroll
  for (int e = 0; e < 8; ++e) u[e] = f2bf(p[e]);
  return __builtin_bit_cast(bf16x8, u);
}

__launch_bounds__(256, 1)
__global__ void k_char_lstm(const int* chars, const float* cemb,
                            const float* cWih_f, const float* cWhh_f, const float* cb_f,
                            const float* cWih_b, const float* cWhh_b, const float* cb_b,
                            const float* h0c, const float* c0c,
                            unsigned char* x8) {
  __shared__ unsigned short embT[128 * 64];
  __shared__ int charsT[16 * 64];
  __shared__ unsigned short hT[64 * 72];
  const int tid = threadIdx.x;
  const int w = tid >> 6, lane = tid & 63;
  const int l15 = lane & 15, lhi = lane >> 4;
  const int sbase = blockIdx.x * 64;

  for (int idx = tid; idx < 8192; idx += 256) embT[idx] = f2bf(cemb[idx]);
  for (int idx = tid; idx < 1024; idx += 256) {
    int s = idx >> 4, t = idx & 15;
    charsT[t * 64 + s] = chars[(sbase + s) * 16 + t];
  }
  for (int idx = tid; idx < 4096; idx += 256) {
    int s = idx >> 6, u = idx & 63;
    hT[s * 72 + u] = f2bf(h0c[(sbase + s) * 64 + u]);
  }
  bf16x8 bih[4][2], bhh[4][2];
  float bias[4];
  #pragma unroll
  for (int q = 0; q < 4; ++q) {
    bias[q] = cb_f[q * 64 + w * 16 + l15];
    #pragma unroll
    for (int ks = 0; ks < 2; ++ks) {
      bih[q][ks] = load_wfrag(cWih_f, (w + 4 * q) * 16, l15, lhi, ks);
      bhh[q][ks] = load_wfrag(cWhh_f, (w + 4 * q) * 16, l15, lhi, ks);
    }
  }
  float c_[4][4];
  #pragma unroll
  for (int mt = 0; mt < 4; ++mt)
    #pragma unroll
    for (int i = 0; i < 4; ++i)
      c_[mt][i] = c0c[(sbase + mt * 16 + lhi * 4 + i) * 64 + w * 16 + l15];
  float hfin[4][4];
  #pragma unroll
  for (int mt = 0; mt < 4; ++mt)
    #pragma unroll
    for (int i = 0; i < 4; ++i) hfin[mt][i] = 0.0f;
  __syncthreads();

  for (int t = 0; t < 16; ++t) {
    bf16x8 ax[4][2], ah[4][2];
    #pragma unroll
    for (int mt = 0; mt < 4; ++mt) {
      int cidx = charsT[t * 64 + mt * 16 + l15];
      #pragma unroll
      for (int ks = 0; ks < 2; ++ks) {
        ax[mt][ks] = __builtin_bit_cast(bf16x8, *(const u16x8*)&embT[cidx * 64 + ks * 32 + lhi * 8]);
        ah[mt][ks] = __builtin_bit_cast(bf16x8, *(const u16x8*)&hT[(mt * 16 + l15) * 72 + ks * 32 + lhi * 8]);
      }
    }
    f32x4 acc[4][4];
    #pragma unroll
    for (int mt = 0; mt < 4; ++mt)
      #pragma unroll
      for (int q = 0; q < 4; ++q) acc[mt][q] = (f32x4){0.f, 0.f, 0.f, 0.f};
    #pragma unroll
    for (int ks = 0; ks < 2; ++ks)
      #pragma unroll
      for (int mt = 0; mt < 4; ++mt)
        #pragma unroll
        for (int q = 0; q < 4; ++q) {
          acc[mt][q] = mfma_bf16(ax[mt][ks], bih[q][ks], acc[mt][q]);
          acc[mt][q] = mfma_bf16(ah[mt][ks], bhh[q][ks], acc[mt][q]);
        }
    __syncthreads();
    #pragma unroll
    for (int mt = 0; mt < 4; ++mt)
      #pragma unroll
      for (int i = 0; i < 4; ++i) {
        float gi = acc[mt][0][i] + bias[0];
        float gf = acc[mt][1][i] + bias[1];
        float gg = acc[mt][2][i] + bias[2];
        float go = acc[mt][3][i] + bias[3];
        float cn = sigf(gf) * c_[mt][i] + sigf(gi) * tanhf_(gg);
        float h = sigf(go) * tanhf_(cn);
        c_[mt][i] = cn;
        if (t == 15) hfin[mt][i] = h;
        hT[(mt * 16 + lhi * 4 + i) * 72 + w * 16 + l15] = f2bf(h);
      }
    __syncthreads();
  }
  #pragma unroll
  for (int mt = 0; mt < 4; ++mt)
    #pragma unroll
    for (int i = 0; i < 4; ++i) {
      int sg = sbase + mt * 16 + lhi * 4 + i;
      int xrow = (sg & 255) * 64 + (sg >> 8);
      int p = __builtin_amdgcn_cvt_pk_fp8_f32(hfin[mt][i] * 16.0f, 0.0f, 0, false);
      x8[xrow * 640 + w * 16 + l15] = (unsigned char)(p & 0xFF);
    }
  #pragma unroll
  for (int q = 0; q < 4; ++q) {
    bias[q] = cb_b[q * 64 + w * 16 + l15];
    #pragma unroll
    for (int ks = 0; ks < 2; ++ks) {
      bih[q][ks] = load_wfrag(cWih_b, (w + 4 * q) * 16, l15, lhi, ks);
      bhh[q][ks] = load_wfrag(cWhh_b, (w + 4 * q) * 16, l15, lhi, ks);
    }
  }
  __syncthreads();
  for (int idx = tid; idx < 4096; idx += 256) {
    int s = idx >> 6, u = idx & 63;
    hT[s * 72 + u] = f2bf(h0c[16384 * 64 + (sbase + s) * 64 + u]);
  }
  __syncthreads();
  {
    bf16x8 ax[4][2], ah[4][2];
    #pragma unroll
    for (int mt = 0; mt < 4; ++mt) {
      int cidx = charsT[15 * 64 + mt * 16 + l15];
      #pragma unroll
      for (int ks = 0; ks < 2; ++ks) {
        ax[mt][ks] = __builtin_bit_cast(bf16x8, *(const u16x8*)&embT[cidx * 64 + ks * 32 + lhi * 8]);
        ah[mt][ks] = __builtin_bit_cast(bf16x8, *(const u16x8*)&hT[(mt * 16 + l15) * 72 + ks * 32 + lhi * 8]);
      }
    }
    f32x4 acc[4][4];
    #pragma unroll
    for (int mt = 0; mt < 4; ++mt)
      #pragma unroll
      for (int q = 0; q < 4; ++q) acc[mt][q] = (f32x4){0.f, 0.f, 0.f, 0.f};
    #pragma unroll
    for (int ks = 0; ks < 2; ++ks)
      #pragma unroll
      for (int mt = 0; mt < 4; ++mt)
        #pragma unroll
        for (int q = 0; q < 4; ++q) {
          acc[mt][q] = mfma_bf16(ax[mt][ks], bih[q][ks], acc[mt][q]);
          acc[mt][q] = mfma_bf16(ah[mt][ks], bhh[q][ks], acc[mt][q]);
        }
    #pragma unroll
    for (int mt = 0; mt < 4; ++mt)
      #pragma unroll
      for (int i = 0; i < 4; ++i) {
        float cc = c0c[16384 * 64 + (sbase + mt * 16 + lhi * 4 + i) * 64 + w * 16 + l15];
        float gi = acc[mt][0][i] + bias[0];
        float gf = acc[mt][1][i] + bias[1];
        float gg = acc[mt][2][i] + bias[2];
        float go = acc[mt][3][i] + bias[3];
        float cn = sigf(gf) * cc + sigf(gi) * tanhf_(gg);
        float h = sigf(go) * tanhf_(cn);
        int sg = sbase + mt * 16 + lhi * 4 + i;
        int xrow = (sg & 255) * 64 + (sg >> 8);
        int p = __builtin_amdgcn_cvt_pk_fp8_f32(h * 16.0f, 0.0f, 0, false);
        x8[xrow * 640 + 64 + w * 16 + l15] = (unsigned char)(p & 0xFF);
      }
  }
}

// ---------------- K3: pre-gates GEMM, MX-fp8 K=128 -------------------------
__launch_bounds__(256, 2)
__global__ void k_gemm_pre(const unsigned char* x8, const unsigned char* w8,
                           const float* wb_f, const float* wb_b,
                           unsigned short* pre2) {
  __shared__ __align__(16) unsigned char ldsA[2][128 * 144];
  __shared__ __align__(16) unsigned char ldsB[2][128 * 144];
  const int tid = threadIdx.x;
  const int bm = blockIdx.x >> 4, bn = blockIdx.x & 15;
  const int m0 = bm * 128, n0 = bn * 128;
  const int lane = tid & 63, w = tid >> 6;
  const int l15 = lane & 15, lhi = lane >> 4;
  const int wm = (w & 1) * 64, wn = (w >> 1) * 64;

  u16x8 ra[4], rb[4];
  auto gload = [&](int kt) {
    #pragma unroll
    for (int i = 0; i < 4; ++i) {
      int c = i * 256 + tid;
      int row = c >> 3, cb = (c & 7) * 16;
      ra[i] = *(const u16x8*)&x8[(m0 + row) * 640 + kt * 128 + cb];
      rb[i] = *(const u16x8*)&w8[(n0 + row) * 640 + kt * 128 + cb];
    }
  };
  auto swrite = [&](int buf) {
    #pragma unroll
    for (int i = 0; i < 4; ++i) {
      int c = i * 256 + tid;
      int row = c >> 3, cb = (c & 7) * 16;
      *(u16x8*)&ldsA[buf][row * 144 + cb] = ra[i];
      *(u16x8*)&ldsB[buf][row * 144 + cb] = rb[i];
    }
  };
  f32x4 acc[4][4];
  #pragma unroll
  for (int a = 0; a < 4; ++a)
    #pragma unroll
    for (int bb = 0; bb < 4; ++bb) acc[a][bb] = (f32x4){0.f, 0.f, 0.f, 0.f};

  gload(0); swrite(0); __syncthreads();
  for (int kt = 0; kt < 5; ++kt) {
    int cur = kt & 1;
    if (kt < 4) gload(kt + 1);
    i32x8 af[4], bfv[4];
    #pragma unroll
    for (int mt = 0; mt < 4; ++mt)
      af[mt] = __builtin_bit_cast(i32x8,
          *(const l64x4*)&ldsA[cur][(wm + mt * 16 + l15) * 144 + lhi * 32]);
    #pragma unroll
    for (int nt = 0; nt < 4; ++nt)
      bfv[nt] = __builtin_bit_cast(i32x8,
          *(const l64x4*)&ldsB[cur][(wn + nt * 16 + l15) * 144 + lhi * 32]);
    #pragma unroll
    for (int mt = 0; mt < 4; ++mt)
      #pragma unroll
      for (int nt = 0; nt < 4; ++nt)
        acc[mt][nt] = mfma_mx(af[mt], bfv[nt], acc[mt][nt]);
    __syncthreads();
    if (kt < 4) { swrite(cur ^ 1); __syncthreads(); }
  }
  const float inv = 1.0f / 256.0f;
  #pragma unroll
  for (int nt = 0; nt < 4; ++nt) {
    int col = n0 + wn + nt * 16 + l15;
    float bias = (col < 1024) ? wb_f[col] : wb_b[col - 1024];
    #pragma unroll
    for (int mt = 0; mt < 4; ++mt) {
      int row = m0 + wm + mt * 16 + lhi * 4;
      int t = row >> 6, b = row & 63, rg = b >> 3, b8 = b & 7;
      u16x4 v;
      #pragma unroll
      for (int i = 0; i < 4; ++i) v[i] = f2bf(acc[mt][nt][i] * inv + bias);
      *(u16x4*)&pre2[((long)(rg * 256 + t) * 2048 + col) * 8 + b8] = v;
    }
  }
}

// ---------------- K4: word LSTM recurrence v9 (fp8 A x fp4 B, 2-way split) -
#define LSTM_STEP(SRC, DST, PU, TT)                                          \
  {                                                                          \
    long a8[8];                                                              \
    _Pragma("unroll")                                                        \
    for (int ks = 0; ks < 8; ++ks)                                           \
      a8[ks] = *(const long*)&SRC[l15 * 264 + ks * 32 + lhi * 8];            \
    l64x4 alo4 = {a8[0], a8[1], a8[2], a8[3]};                               \
    l64x4 ahi4 = {a8[4], a8[5], a8[6], a8[7]};                               \
    i32x8 aLo = __builtin_bit_cast(i32x8, alo4);                             \
    i32x8 aHi = __builtin_bit_cast(i32x8, ahi4);                             \
    f32x4 accA[4], accB[4];                                                  \
    _Pragma("unroll")                                                        \
    for (int g = 0; g < 4; ++g) {                                            \
      accA[g] = mfma_mx4(aLo, bfr4[g][0], (f32x4){0.f, 0.f, 0.f, 0.f});      \
      accB[g] = mfma_mx4(aHi, bfr4[g][1], (f32x4){0.f, 0.f, 0.f, 0.f});      \
    }                                                                        \
    float gi = fmaf(accA[0][0] + accB[0][0], inv, bf2f(PU[0]));              \
    float gf = fmaf(accA[1][0] + accB[1][0], inv, bf2f(PU[1]));              \
    float gg = fmaf(accA[2][0] + accB[2][0], inv, bf2f(PU[2]));              \
    float go = fmaf(accA[3][0] + accB[3][0], inv, bf2f(PU[3]));              \
    float cn = sigf(gf) * c1 + sigf(gi) * tanhf_(gg);                        \
    float h = sigf(go) * tanhf_(cn);                                         \
    c1 = cn;                                                                 \
    int p2 = __builtin_amdgcn_cvt_pk_fp8_f32(h * 16.0f, 0.0f, 0, false);     \
    DST[(4 * lhi) * 264 + uu] = (unsigned char)(p2 & 0xFF);                  \
    hout[((long)(TT) * 64 + row0 + lhi) * 512 + dco] = f2bf(h);              \
  }

__launch_bounds__(1024, 4)
__global__ void k_word_lstm(const unsigned char* whh4, const unsigned short* pre2,
                            const float* h0w, const float* c0w,
                            unsigned short* hout, float* cstate, int t0) {
  __shared__ __align__(16) unsigned char hlds[2][16 * 264];   // fp8 h, x16 scale
  const int tid = threadIdx.x;
  const int w = tid >> 6, lane = tid & 63;
  const int l15 = lane & 15, lhi = lane >> 4;
  const int dir = blockIdx.x >> 4, rg = blockIdx.x & 15;
  const int row0 = rg * 4;
  const int uu = w * 16 + l15;
  const int dco = dir * 256 + uu;
  const bool first = (t0 == 0);
  const unsigned char* W4 = whh4 + dir * 131072;

  i32x8 bfr4[4][2];   // resident fp4 weights (16B each, low 4 dwords)
  #pragma unroll
  for (int g = 0; g < 4; ++g) {
    int grow = g * 256 + uu;
    #pragma unroll
    for (int kt = 0; kt < 2; ++kt) {
      l64x2 v2 = *(const l64x2*)(W4 + grow * 128 + kt * 64 + lhi * 16);
      l64x4 v = {v2[0], v2[1], 0, 0};
      bfr4[g][kt] = __builtin_bit_cast(i32x8, v);
    }
  }
  for (int idx = tid; idx < 2112; idx += 1024)
    ((unsigned int*)&hlds[0][0])[idx] = 0;
  __syncthreads();
  {
    int r = tid >> 8, u0 = tid & 255;
    float hv;
    if (first) {
      hv = h0w[dir * 16384 + (row0 + r) * 256 + u0];
    } else {
      int tb = dir ? (256 - t0) : (t0 - 1);
      hv = bf2f(hout[((long)tb * 64 + row0 + r) * 512 + dir * 256 + u0]);
    }
    int p = __builtin_amdgcn_cvt_pk_fp8_f32(hv * 16.0f, 0.0f, 0, false);
    hlds[0][(4 * r) * 264 + u0] = (unsigned char)(p & 0xFF);
  }
  float c1 = first ? c0w[dir * 16384 + (row0 + lhi) * 256 + uu]
                   : cstate[blockIdx.x * 1024 + tid];

  const unsigned short* pgBase =
      pre2 + (long)(rg >> 1) * 256 * 2048 * 8 + (dir * 1024 + uu) * 8 + (rg & 1) * 4 + lhi;

  unsigned short pA[4], pB[4];
  const int ttA0 = dir ? (255 - t0) : t0;
  #pragma unroll
  for (int g = 0; g < 4; ++g)
    pA[g] = pgBase[(long)ttA0 * 16384 + g * 2048];
  __syncthreads();

  const float inv = 1.0f / 256.0f;
  for (int tl = 0; tl < 128; tl += 2) {
    const int tg = t0 + tl;
    const int ttA = dir ? (255 - tg) : tg;
    const int ttB = dir ? (254 - tg) : (tg + 1);
    int ttC = dir ? (253 - tg) : (tg + 2);
    ttC = ttC < 0 ? 0 : (ttC > 255 ? 255 : ttC);
    #pragma unroll
    for (int g = 0; g < 4; ++g)
      pB[g] = pgBase[(long)ttB * 16384 + g * 2048];
    LSTM_STEP(hlds[0], hlds[1], pA, ttA)
    lds_barrier();
    #pragma unroll
    for (int g = 0; g < 4; ++g)
      pA[g] = pgBase[(long)ttC * 16384 + g * 2048];
    LSTM_STEP(hlds[1], hlds[0], pB, ttB)
    lds_barrier();
  }
  cstate[blockIdx.x * 1024 + tid] = c1;
}

// ---------------- K5: feats + gold fold ------------------------------------
__launch_bounds__(256, 2)
__global__ void k_feats(const unsigned short* hbuf, const float* Wtag, const float* btag,
                        const int* tags, const float* trans,
                        float* feats, float* goldacc) {
  __shared__ float red[256];
  const int tid = threadIdx.x;
  const int w = tid >> 6, lane = tid & 63, l15 = lane & 15, lhi = lane >> 4;
  const int m0 = blockIdx.x * 64 + w * 16;
  const int t = blockIdx.x;
  bf16x8 bfr[16];
  #pragma unroll
  for (int ks = 0; ks < 16; ++ks) {
    u16x8 u;
    if (l15 < 12) {
      const float* p = Wtag + l15 * 512 + ks * 32 + lhi * 8;
      #pragma unroll
      for (int e = 0; e < 8; ++e) u[e] = f2bf(p[e]);
    } else {
      #pragma unroll
      for (int e = 0; e < 8; ++e) u[e] = 0;
    }
    bfr[ks] = __builtin_bit_cast(bf16x8, u);
  }
  f32x4 acc = {0.f, 0.f, 0.f, 0.f};
  #pragma unroll
  for (int ks = 0; ks < 16; ++ks) {
    u16x8 a = *(const u16x8*)&hbuf[(m0 + l15) * 512 + ks * 32 + lhi * 8];
    acc = mfma_bf16(__builtin_bit_cast(bf16x8, a), bfr[ks], acc);
  }
  float bias = (l15 < 12) ? btag[l15] : 0.0f;
  float g = 0.0f;
  #pragma unroll
  for (int i = 0; i < 4; ++i) {
    float fv = acc[i] + bias;
    feats[(m0 + lhi * 4 + i) * 16 + l15] = fv;
    int b = w * 16 + lhi * 4 + i;          // batch index (block = one t)
    int tg = tags[b * 256 + t];
    if (l15 == tg) g += fv;
    if (l15 == 0) {
      int pv = (t == 0) ? 0 : tags[b * 256 + t - 1];
      g += trans[tg * 12 + pv];
      if (t == 255) g += trans[2 * 12 + tg];
    }
  }
  red[tid] = g;
  __syncthreads();
  for (int st = 128; st > 0; st >>= 1) {
    if (tid < st) red[tid] += red[tid + st];
    __syncthreads();
  }
  if (tid == 0) atomicAdd(goldacc, red[0]);
}

// ---------------- K6: CRF v5 — packed-f32 exp-domain, gold pre-folded ------
#define LOADE2(R)                                                            \
  _Pragma("unroll")                                                          \
  for (int k = 0; k < 6; ++k) {                                              \
    E##R[k][0] = __builtin_amdgcn_exp2f(LOG2E * trans[R * 12 + 2 * k]);      \
    E##R[k][1] = __builtin_amdgcn_exp2f(LOG2E * trans[R * 12 + 2 * k + 1]);  \
  }
#define DOTE2(R)                                                             \
  {                                                                          \
    f32x2 d2 = E##R[0] * pv[0];                                              \
    _Pragma("unroll")                                                        \
    for (int k = 1; k < 6; ++k)                                              \
      d2 = __builtin_elementwise_fma(E##R[k], pv[k], d2);                    \
    np[R] = em[R] * (d2[0] + d2[1]);                                         \
  }

__launch_bounds__(64, 1)
__global__ void k_crf(const float* feats, const float* trans, const float* goldacc,
                      float* out) {
  const int lane = threadIdx.x;   // batch 0..63
  const float LOG2E = 1.44269504089f, LN2 = 0.69314718056f;
  f32x2 E0[6], E1[6], E2[6], E3[6], E4[6], E5[6],
        E6[6], E7[6], E8[6], E9[6], E10[6], E11[6];
  float tr2[12];
  LOADE2(0) LOADE2(1) LOADE2(2) LOADE2(3) LOADE2(4) LOADE2(5)
  LOADE2(6) LOADE2(7) LOADE2(8) LOADE2(9) LOADE2(10) LOADE2(11)
  #pragma unroll
  for (int j = 0; j < 12; ++j) tr2[j] = trans[2 * 12 + j];

  f32x2 pv[6];
  pv[0] = (f32x2){1.0f, 0.0f};
  #pragma unroll
  for (int k = 1; k < 6; ++k) pv[k] = (f32x2){0.0f, 0.0f};
  float logZ = 0.0f;
  const float* fp = feats + lane * 16;
  f32x4 c0 = *(const f32x4*)(fp);
  f32x4 c1 = *(const f32x4*)(fp + 4);
  f32x4 c2 = *(const f32x4*)(fp + 8);
  for (int t = 0; t < 256; ++t) {
    const float* npf = fp + (long)(t + 1) * 1024;   // t=255 strays into wcat8, ok
    f32x4 n0 = *(const f32x4*)(npf);
    f32x4 n1 = *(const f32x4*)(npf + 4);
    f32x4 n2 = *(const f32x4*)(npf + 8);
    float em[12];
    em[0] = __builtin_amdgcn_exp2f(LOG2E * c0[0]);
    em[1] = __builtin_amdgcn_exp2f(LOG2E * c0[1]);
    em[2] = __builtin_amdgcn_exp2f(LOG2E * c0[2]);
    em[3] = __builtin_amdgcn_exp2f(LOG2E * c0[3]);
    em[4] = __builtin_amdgcn_exp2f(LOG2E * c1[0]);
    em[5] = __builtin_amdgcn_exp2f(LOG2E * c1[1]);
    em[6] = __builtin_amdgcn_exp2f(LOG2E * c1[2]);
    em[7] = __builtin_amdgcn_exp2f(LOG2E * c1[3]);
    em[8] = __builtin_amdgcn_exp2f(LOG2E * c2[0]);
    em[9] = __builtin_amdgcn_exp2f(LOG2E * c2[1]);
    em[10] = __builtin_amdgcn_exp2f(LOG2E * c2[2]);
    em[11] = __builtin_amdgcn_exp2f(LOG2E * c2[3]);
    float np[12];
    DOTE2(0) DOTE2(1) DOTE2(2) DOTE2(3) DOTE2(4) DOTE2(5)
    DOTE2(6) DOTE2(7) DOTE2(8) DOTE2(9) DOTE2(10) DOTE2(11)
    if ((t & 3) == 3) {       // renormalize
      float s = fmaxf(fmaxf(
          fmaxf(fmaxf(np[0], np[1]), fmaxf(np[2], np[3])),
          fmaxf(fmaxf(np[4], np[5]), fmaxf(np[6], np[7]))),
          fmaxf(fmaxf(np[8], np[9]), fmaxf(np[10], np[11])));
      float r = __builtin_amdgcn_rcpf(s);
      #pragma unroll
      for (int j = 0; j < 12; ++j) np[j] *= r;
      logZ += __builtin_amdgcn_logf(s);
    }
    #pragma unroll
    for (int k = 0; k < 6; ++k) pv[k] = (f32x2){np[2 * k], np[2 * k + 1]};
    c0 = n0; c1 = n1; c2 = n2;
  }
  float s = 0.0f;
  #pragma unroll
  for (int k = 0; k < 6; ++k) {
    s = fmaf(pv[k][0], __builtin_amdgcn_exp2f(LOG2E * tr2[2 * k]), s);
    s = fmaf(pv[k][1], __builtin_amdgcn_exp2f(LOG2E * tr2[2 * k + 1]), s);
  }
  float part = LN2 * (logZ + __builtin_amdgcn_logf(s));
  #pragma unroll
  for (int d = 1; d < 64; d <<= 1) part += __shfl_xor(part, d, 64);
  if (lane == 0) out[0] = (part - goldacc[0]) / 64.0f;
}

// ---------------------------------------------------------------------------
extern "C" void kernel_launch(void* const* d_in, const int* in_sizes, int n_in,
                              void* d_out, int out_size, void* d_ws, size_t ws_size,
                              hipStream_t stream) {
  const int*   sentence = (const int*)d_in[0];
  const int*   chars    = (const int*)d_in[1];
  const int*   tags     = (const int*)d_in[2];
  const float* wemb     = (const float*)d_in[3];
  const float* cemb     = (const float*)d_in[4];
  const float* cWih_f   = (const float*)d_in[5];
  const float* cWhh_f   = (const float*)d_in[6];
  const float* cb_f     = (const float*)d_in[7];
  const float* cWih_b   = (const float*)d_in[8];
  const float* cWhh_b   = (const float*)d_in[9];
  const float* cb_b     = (const float*)d_in[10];
  const float* wWih_f   = (const float*)d_in[11];
  const float* wWhh_f   = (const float*)d_in[12];
  const float* wb_f     = (const float*)d_in[13];
  const float* wWih_b   = (const float*)d_in[14];
  const float* wWhh_b   = (const float*)d_in[15];
  const float* wb_b     = (const float*)d_in[16];
  const float* Wtag     = (const float*)d_in[17];
  const float* btag     = (const float*)d_in[18];
  const float* trans    = (const float*)d_in[19];
  const float* h0c      = (const float*)d_in[20];
  const float* c0c      = (const float*)d_in[21];
  const float* h0w      = (const float*)d_in[22];
  const float* c0w      = (const float*)d_in[23];

  char* ws = (char*)d_ws;
  unsigned char*  x8    = (unsigned char*)(ws);                  // 10,485,760 B
  unsigned short* pre2  = (unsigned short*)(ws + 20971520);      // 67,108,864 B
  unsigned short* hbuf  = (unsigned short*)(ws + 88080384);      // 16,777,216 B
  float*          feats = (float*)(ws + 104857600);              //  1,048,576 B
  unsigned short* wcat8 = (unsigned short*)(ws + 105906176);     //  1,310,720 B (fp8)
  unsigned char*  whh4  = (unsigned char*)(ws + 108527616);      //    262,144 B (fp4)
  float*          cstate= (float*)(ws + 108789760);              //    131,072 B
  float*          goldacc = (float*)(ws + 108920832);            //          4 B

  hipLaunchKernelGGL(k_prep, dim3(7680), dim3(256), 0, stream,
                     wWih_f, wWih_b, wWhh_f, wWhh_b, sentence, wemb, wcat8, whh4, x8,
                     goldacc);
  hipLaunchKernelGGL(k_char_lstm, dim3(256), dim3(256), 0, stream, chars, cemb,
                     cWih_f, cWhh_f, cb_f, cWih_b, cWhh_b, cb_b, h0c, c0c, x8);
  hipLaunchKernelGGL(k_gemm_pre, dim3(2048), dim3(256), 0, stream,
                     x8, (const unsigned char*)wcat8, wb_f, wb_b, pre2);
  hipLaunchKernelGGL(k_word_lstm, dim3(32), dim3(1024), 0, stream,
                     whh4, pre2, h0w, c0w, hbuf, cstate, 0);
  hipLaunchKernelGGL(k_word_lstm, dim3(32), dim3(1024), 0, stream,
                     whh4, pre2, h0w, c0w, hbuf, cstate, 128);
  hipLaunchKernelGGL(k_feats, dim3(256), dim3(256), 0, stream, hbuf, Wtag, btag,
                     tags, trans, feats, goldacc);
  hipLaunchKernelGGL(k_crf, dim3(1), dim3(64), 0, stream, feats, trans, goldacc,
                     (float*)d_out);
}